// Round 8
// baseline (154.020 us; speedup 1.0000x reference)
//
#include <hip/hip_runtime.h>
#include <hip/hip_bf16.h>
#include <stdint.h>

// y[c,k] = sum_{a,b} E1[k,a] * Xc[c,a,b] * E2[k,b],  Xc = C*x, E = exp(i*angle*g)
//
// R8: barrier-free per-wave pipeline. R5 vs R7 proved the per-tile stall is
// the BARRIER RENDEZVOUS, not buffer depth. Structure exploits two facts:
//   (a) wave w's A rows are consumed ONLY by wave w  -> private LDS dbuf,
//       staged by the wave itself via global_load_lds (fire-and-forget);
//   (b) B is tiny (4KB/tile) -> per-wave REGISTERS, 4 global_load_dwordx4
//       per tile prefetched ONE TILE AHEAD (R6 failed with 16 UNprefetched
//       loads; 4 prefetched is a different regime).
// => NO __syncthreads in the K-loop. Each wave: issue 12 VMEM (8 A-stage +
//    4 B-frag) for tile t+1, s_waitcnt vmcnt(12) (== tile-t data complete,
//    since exactly 12 VMEM issue per iter), ds_read + 32 MFMA. Waves slide
//    freely -> MFMA pipe fed continuously (T4 counted-vmcnt without the
//    lockstep that sank R3).
// Work cut: B col j=0 is cos(0)=1 for ALL k -> its rank-1 term is a
// k-independent per-row bias, folded into the ACC INIT (acc=bias, not 0).
// K shrinks 288->256 = 8 tiles, no zero padding (-11% MFMA+staging).
//
// A layout per (c,a): A_re row a   = [Re XcC[j] | -Im XcS[j]], j=1..128
//                     A_im row 256+a = [Im XcC[j] |  Re XcS[j]]
//   XcC[j]=Xc[128+j]+Xc[128-j], XcS[j]=Xc[128+j]-Xc[128-j] (j=1..127)
//   XcC[128]=Xc[b=0], XcS[128]=-Xc[b=0];  bias row m = Xc[a,b=128] (Re/Im)
// B row k = [cos(t j) | sin(t j)], j=1..128 (256 cols, row-major).

#define NKTOT 17408
#define NBLK 272    // ktiles of 64 k-values
#define NT 8        // K-tiles of 32 (K = 256 exactly)
#define LDB 256

typedef short bf16x8 __attribute__((ext_vector_type(8)));
typedef float f32x4 __attribute__((ext_vector_type(4)));

#define WAITVM(N) asm volatile("s_waitcnt vmcnt(" #N ")" ::: "memory")

__device__ __forceinline__ unsigned short f2bf(float f) {
  unsigned int u = __builtin_bit_cast(unsigned int, f);
  u += 0x7FFFu + ((u >> 16) & 1u);
  return (unsigned short)(u >> 16);
}
__device__ __forceinline__ float bf2f(unsigned int lo16) {
  return __builtin_bit_cast(float, lo16 << 16);
}

__device__ __forceinline__ void async_copy16(void* lds, const void* g) {
  __builtin_amdgcn_global_load_lds(
      (const __attribute__((address_space(1))) unsigned int*)g,
      (__attribute__((address_space(3))) unsigned int*)lds, 16, 0, 0);
}

// A image: [c][tt<8][w<4][pl<64][s<8][e<8] ushorts.
//   logical row m (0..511): w=m>>7, ml=m&127, pl=ml>>1
//   col jj (0..255): tt=jj>>5, s=((ml&1)<<2)|((jj>>3)&3), e=jj&7
__device__ __forceinline__ size_t aidx(int c, int m, int jj) {
  int w = m >> 7, ml = m & 127;
  int tt = jj >> 5;
  int s = ((ml & 1) << 2) | ((jj >> 3) & 3);
  return ((((size_t)(c * 8 + tt) * 4 + w) * 64 + (ml >> 1)) * 8 + s) * 8 + (jj & 7);
}

// Fused packing. Blocks 0..1023: fold A (2 (c,a) rows per block).
// Blocks 1024..18431: one k each -> B row + E1 row.
__global__ __launch_bounds__(256) void pack_all(
    const float* __restrict__ input_r, const float* __restrict__ C_r,
    const float* __restrict__ angle,
    unsigned short* __restrict__ Apack, unsigned short* __restrict__ BT,
    float* __restrict__ biastab, unsigned int* __restrict__ E1tab)
{
  const int bx = blockIdx.x;
  const int tid = threadIdx.x;
  if (bx < 1024) {
    const int p = bx * 2 + (tid >> 7);   // (c,a) pair index 0..2047
    const int a = p & 255;
    const int c = p >> 8;
    const int j = tid & 127;
    const size_t xbase = (size_t)a * 256;
    const size_t cbase = ((size_t)(c * 256 + a)) * 256;
    if (j == 0) {
      // bias (b=128, g=0 term) and the j=128 fold (b=0, unpaired g=-128)
      float xr = input_r[(xbase + 128) * 2], xi = input_r[(xbase + 128) * 2 + 1];
      float cr = C_r[(cbase + 128) * 2],     ci = C_r[(cbase + 128) * 2 + 1];
      biastab[c * 512 + a]       = cr * xr - ci * xi;   // Re Xc[a,128]
      biastab[c * 512 + 256 + a] = cr * xi + ci * xr;   // Im Xc[a,128]
      xr = input_r[xbase * 2]; xi = input_r[xbase * 2 + 1];
      cr = C_r[cbase * 2];     ci = C_r[cbase * 2 + 1];
      float reb = cr * xr - ci * xi, imb = cr * xi + ci * xr;   // Xc[a,0]
      Apack[aidx(c, a, 127)]       = f2bf(reb);    // Re XcC[128]
      Apack[aidx(c, a, 255)]       = f2bf(imb);    // -Im XcS[128] = +Im Xc0
      Apack[aidx(c, 256 + a, 127)] = f2bf(imb);    // Im XcC[128]
      Apack[aidx(c, 256 + a, 255)] = f2bf(-reb);   // Re XcS[128] = -Re Xc0
    } else {
      const int bp = 128 + j, bm = 128 - j;
      float xpr = input_r[(xbase + bp) * 2], xpi = input_r[(xbase + bp) * 2 + 1];
      float cpr = C_r[(cbase + bp) * 2],     cpi = C_r[(cbase + bp) * 2 + 1];
      float pr = cpr * xpr - cpi * xpi, pi = cpr * xpi + cpi * xpr;
      float xmr = input_r[(xbase + bm) * 2], xmi = input_r[(xbase + bm) * 2 + 1];
      float cmr = C_r[(cbase + bm) * 2],     cmi = C_r[(cbase + bm) * 2 + 1];
      float mrv = cmr * xmr - cmi * xmi, miv = cmr * xmi + cmi * xmr;
      Apack[aidx(c, a, j - 1)]           = f2bf(pr + mrv);   //  Re XcC[j]
      Apack[aidx(c, a, 127 + j)]         = f2bf(miv - pi);   // -Im XcS[j]
      Apack[aidx(c, 256 + a, j - 1)]     = f2bf(pi + miv);   //  Im XcC[j]
      Apack[aidx(c, 256 + a, 127 + j)]   = f2bf(pr - mrv);   //  Re XcS[j]
    }
  } else {
    const int k = bx - 1024;             // 0..17407
    const float s = angle[k * 2 + 0];
    const float t = angle[k * 2 + 1];
    float sn, cs;
    __sincosf(s * (float)(tid - 128), &sn, &cs);   // E1[k, a=tid]
    E1tab[(size_t)k * 256 + tid] =
        (unsigned int)f2bf(cs) | ((unsigned int)f2bf(sn) << 16);
    if (tid >= 1 && tid <= 128) {
      __sincosf(t * (float)tid, &sn, &cs);
      BT[(size_t)k * LDB + tid - 1]   = f2bf(cs);   // cos cols 0..127
      BT[(size_t)k * LDB + 127 + tid] = f2bf(sn);   // sin cols 128..255
    }
  }
}

__global__ __launch_bounds__(256, 2) void gemm_fused(
    const unsigned short* __restrict__ Apack,
    const unsigned short* __restrict__ BT,
    const float* __restrict__ biastab,
    const unsigned int* __restrict__ E1tab,
    const float* __restrict__ wvec,
    float* __restrict__ out)
{
  __shared__ unsigned short As[4][2][4096];  // per-wave private 2x8KB dbuf
  __shared__ float scol[4][2][64];           // 2KB  => 66KB -> 2 blocks/CU

  // XCD-aware decode: bx%8 == ktile%8 keeps all 8 c-blocks of one ktile on
  // the same XCD. 2176 = 34*64 -> bijective.
  const int bx = blockIdx.x;
  const int c = (bx >> 3) & 7;
  const int ktile = (bx >> 6) * 8 + (bx & 7);   // 0..271
  const int kt0 = ktile * 64;
  const int tid = threadIdx.x;
  const int w = tid >> 6;       // 0..3: owns logical rows w*128..+127
  const int l = tid & 63;
  const int lhi = l >> 4;       // 0..3
  const int llo = l & 15;
  const int lr = l >> 3;                      // staging: phys row within chunk
  const int lsw = ((l & 7) ^ lr) * 8;         // staging: swizzled source slot

  // per-wave global A base: [c][tt][w] tiles of 4096 ush; tile stride 16384
  const unsigned short* Aimg = Apack + ((size_t)c * 32 + w) * 4096;
  // per-lane B base: row k = kt0 + fj*16 + llo, elems tt*32 + lhi*8 ..+7
  const unsigned short* Bw = BT + ((size_t)kt0 + llo) * LDB + lhi * 8;
  const float* biasp = biastab + c * 512 + w * 128 + lhi * 4;

  // LDS fragment read: phys row pl = fi*8 + (llo>>1), slot u = s ^ (pl&7),
  // s = ((llo&1)<<2)|lhi
  const int u8 = (((((llo & 1) << 2) | lhi)) ^ ((llo >> 1) & 7)) * 8;
  const int plbase = (llo >> 1);

  f32x4 acc[8][4];
  bf16x8 bfrag[2][4];

  // Prologue (NO barrier): bias loads + tile-0 staging; the first counted
  // wait in iter 0 covers them (they are the oldest VMEM ops).
#pragma unroll
  for (int i = 0; i < 8; ++i)
    async_copy16(&As[w][0][i * 512], Aimg + (size_t)(i * 8 + lr) * 64 + lsw);
#pragma unroll
  for (int fj = 0; fj < 4; ++fj)
    bfrag[0][fj] = *(const bf16x8*)(Bw + (size_t)fj * 16 * LDB);
  // acc init = bias (the folded cos-col-0 rank-1 term); k-independent.
#pragma unroll
  for (int fi = 0; fi < 8; ++fi) {
    f32x4 b4 = *(const f32x4*)(biasp + fi * 16);
#pragma unroll
    for (int fj = 0; fj < 4; ++fj) acc[fi][fj] = b4;
  }

#pragma unroll
  for (int t = 0; t < NT; ++t) {
    const int cu = t & 1;
    const int nx = cu ^ 1;
    __builtin_amdgcn_sched_barrier(0);
    if (t < NT - 1) {
      // issue tile t+1: 8 A-stages (private LDS) + 4 B-frag loads (regs)
#pragma unroll
      for (int i = 0; i < 8; ++i)
        async_copy16(&As[w][nx][i * 512],
                     Aimg + (size_t)(t + 1) * 16384 + (i * 8 + lr) * 64 + lsw);
#pragma unroll
      for (int fj = 0; fj < 4; ++fj)
        bfrag[nx][fj] = *(const bf16x8*)(Bw + (size_t)fj * 16 * LDB + (t + 1) * 32);
      __builtin_amdgcn_sched_barrier(0);
      WAITVM(12);   // everything older than the 12 just issued == tile t ready
    } else {
      __builtin_amdgcn_sched_barrier(0);
      WAITVM(0);    // last tile: drain
    }
    __builtin_amdgcn_sched_barrier(0);
    bf16x8 af[8];
#pragma unroll
    for (int fi = 0; fi < 8; ++fi)
      af[fi] = *(const bf16x8*)&As[w][cu][(fi * 8 + plbase) * 64 + u8];
#pragma unroll
    for (int fi = 0; fi < 8; ++fi)
#pragma unroll
      for (int fj = 0; fj < 4; ++fj)
        acc[fi][fj] = __builtin_amdgcn_mfma_f32_16x16x32_bf16(
            af[fi], bfrag[cu][fj], acc[fi][fj], 0, 0, 0);
  }

  // Epilogue: wave w holds T rows (w<2: Tr, w>=2: Ti), a-half = (w&1)*128.
  const int ahalf = (w & 1) * 128;
#pragma unroll
  for (int fj = 0; fj < 4; ++fj) {
    const int col = fj * 16 + llo;
    const int k = kt0 + col;
    float sumr = 0.f, sumi = 0.f;
    const unsigned int* e1base = E1tab + (size_t)k * 256 + ahalf + lhi * 4;
#pragma unroll
    for (int fi = 0; fi < 8; ++fi) {
      uint4 e4 = *(const uint4*)(e1base + fi * 16);
      unsigned int ev[4] = {e4.x, e4.y, e4.z, e4.w};
#pragma unroll
      for (int r = 0; r < 4; ++r) {
        float v = acc[fi][fj][r];     // T at (a = ahalf + fi*16 + lhi*4 + r, k)
        sumr += bf2f(ev[r] & 0xFFFFu) * v;
        sumi += bf2f(ev[r] >> 16) * v;
      }
    }
    sumr += __shfl_xor(sumr, 16, 64);
    sumr += __shfl_xor(sumr, 32, 64);
    sumi += __shfl_xor(sumi, 16, 64);
    sumi += __shfl_xor(sumi, 32, 64);
    if (lhi == 0) {
      scol[w][0][col] = sumr;
      scol[w][1][col] = sumi;
    }
  }
  __syncthreads();   // the ONLY block-wide barrier
  if (tid < 128) {
    const int col = tid >> 1;
    const int comp = tid & 1;
    const int k = kt0 + col;
    // Re = S_rr(w0)+S_rr(w1) - S_ii(w2)-S_ii(w3)
    // Im = S_ri(w0)+S_ri(w1) + S_ir(w2)+S_ir(w3)
    float re = scol[0][0][col] + scol[1][0][col]
             - scol[2][1][col] - scol[3][1][col];
    float im = scol[0][1][col] + scol[1][1][col]
             + scol[2][0][col] + scol[3][0][col];
    float val = comp ? im : re;
    out[((size_t)c * NKTOT + k) * 2 + comp] = val * wvec[k & 511];
  }
}

extern "C" void kernel_launch(void* const* d_in, const int* in_sizes, int n_in,
                              void* d_out, int out_size, void* d_ws, size_t ws_size,
                              hipStream_t stream) {
  const float* input_r = (const float*)d_in[0];  // (256,256,2)
  const float* C_r     = (const float*)d_in[1];  // (8,256,256,2)
  const float* wvec    = (const float*)d_in[2];  // (512,)
  const float* angle   = (const float*)d_in[3];  // (17408,2)
  float* out = (float*)d_out;                    // (8,17408,2)

  // workspace: Apack 2MB | BT 17408*256*2 = 8.9MB | biastab 16KB |
  //            E1tab 17408*256*4 = 17.8MB  => ~28.8MB
  unsigned short* Apack = (unsigned short*)d_ws;
  unsigned short* BT    = (unsigned short*)((char*)d_ws + (size_t)2097152);
  float*          biastab = (float*)((char*)d_ws + (size_t)2097152 + 8912896);
  unsigned int*   E1tab = (unsigned int*)((char*)d_ws + (size_t)2097152 + 8912896 + 16384);

  pack_all<<<1024 + NKTOT, 256, 0, stream>>>(input_r, C_r, angle,
                                             Apack, BT, biastab, E1tab);
  gemm_fused<<<8 * NBLK, 256, 0, stream>>>(Apack, BT, biastab, E1tab, wvec, out);
}

// Round 9
// 138.885 us; speedup vs baseline: 1.1090x; 1.1090x over previous
//
#include <hip/hip_runtime.h>
#include <hip/hip_bf16.h>
#include <stdint.h>

// y[c,k] = sum_{a,b} E1[k,a] * Xc[c,a,b] * E2[k,b],  Xc = C*x, E = exp(i*angle*g)
//
// R9 = R7's proven schedule (dbuf gload_lds staging, per-tile __syncthreads,
// pre-tiled images, chunk-XOR swizzle, XCD decode) with the RESOURCE SHAPE
// changed to attack the diagnosed limiter (latency-hiding capacity):
//  - R7 vs R8 isolated it: barriers and buffer depth don't matter; occupancy
//    does (all pipes idle at 2 waves/SIMD). acc[8][4]=128 regs capped us there.
//  - Wave tile 64x64 -> acc[4][4]=64 regs, ~116 total -> 4 waves/SIMD at
//    __launch_bounds__(512,4). 8-wave blocks, BM=512, 76KB LDS -> 2 blocks/CU
//    = 16 waves/CU, 2x R7. Same grid, same per-block work, in-block epilogue.
//  - K=256 via R8's bias fold (B col j=0 is cos(0)=1 for all k -> rank-1
//    term folded into acc INIT): 8 tiles, no zero-pad, -11% work vs R7.
//  - A chunks are wave-private (wave w stages+reads phys rows w*32..+31);
//    only the tiny shared B tile needs the barrier.
//
// A content per (c,a): A_re row a     = [Re XcC[j] | -Im XcS[j]], j=1..128
//                      A_im row 256+a = [Im XcC[j] |  Re XcS[j]]
//   XcC[j]=Xc[128+j]+Xc[128-j], XcS[j]=Xc[128+j]-Xc[128-j] (j=1..127)
//   XcC[128]=Xc[b=0], XcS[128]=-Xc[b=0];  bias row m = Xc[a,b=128] comps
// B row k = [cos(t j) j=1..128 | sin(t j) j=1..128]  (256 cols).

#define NKTOT 17408
#define NBLK 272    // ktiles of 64 k-values
#define NT 8        // K-tiles of 32 (K = 256 exactly)

typedef short bf16x8 __attribute__((ext_vector_type(8)));
typedef float f32x4 __attribute__((ext_vector_type(4)));

__device__ __forceinline__ unsigned short f2bf(float f) {
  unsigned int u = __builtin_bit_cast(unsigned int, f);
  u += 0x7FFFu + ((u >> 16) & 1u);
  return (unsigned short)(u >> 16);
}
__device__ __forceinline__ float bf2f(unsigned int lo16) {
  return __builtin_bit_cast(float, lo16 << 16);
}

__device__ __forceinline__ void async_copy16(void* lds, const void* g) {
  __builtin_amdgcn_global_load_lds(
      (const __attribute__((address_space(1))) unsigned int*)g,
      (__attribute__((address_space(3))) unsigned int*)lds, 16, 0, 0);
}

// A image: [c][tt<8][p<256][s<8][e<8] ushorts (slot-linear; staging permutes
// the SOURCE slot, reads apply the XOR -> LDS ends up read-swizzled).
//   logical row m (0..511): p=m>>1 ; col jj (0..255): tt=jj>>5,
//   s=((m&1)<<2)|((jj>>3)&3), e=jj&7
__device__ __forceinline__ size_t aidx(int c, int m, int jj) {
  int tt = jj >> 5;
  int s = ((m & 1) << 2) | ((jj >> 3) & 3);
  return (((size_t)(c * 8 + tt) * 256 + (m >> 1)) * 8 + s) * 8 + (jj & 7);
}
// B image: [ktile<272][tt<8][p<32][s<8][e<8]; k-col kl=2p+(s>=4)
__device__ __forceinline__ size_t bidx(int kt, int kl, int jj) {
  int tt = jj >> 5;
  int s = ((kl & 1) << 2) | ((jj >> 3) & 3);
  return (((size_t)(kt * 8 + tt) * 32 + (kl >> 1)) * 8 + s) * 8 + (jj & 7);
}

// Fused packing. Blocks 0..1023: fold A (2 (c,a) rows per block) + bias.
// Blocks 1024..18431: one k each -> B image row + E1 row.
__global__ __launch_bounds__(256) void pack_all(
    const float* __restrict__ input_r, const float* __restrict__ C_r,
    const float* __restrict__ angle,
    unsigned short* __restrict__ Apack, unsigned short* __restrict__ BT,
    float* __restrict__ biastab, unsigned int* __restrict__ E1tab)
{
  const int bx = blockIdx.x;
  const int tid = threadIdx.x;
  if (bx < 1024) {
    const int p = bx * 2 + (tid >> 7);   // (c,a) pair index 0..2047
    const int a = p & 255;
    const int c = p >> 8;
    const int j = tid & 127;
    const size_t xbase = (size_t)a * 256;
    const size_t cbase = ((size_t)(c * 256 + a)) * 256;
    if (j == 0) {
      // bias (b=128, g=0) and the unpaired b=0 (g=-128) fold
      float xr = input_r[(xbase + 128) * 2], xi = input_r[(xbase + 128) * 2 + 1];
      float cr = C_r[(cbase + 128) * 2],     ci = C_r[(cbase + 128) * 2 + 1];
      biastab[c * 512 + a]       = cr * xr - ci * xi;   // Re Xc[a,128]
      biastab[c * 512 + 256 + a] = cr * xi + ci * xr;   // Im Xc[a,128]
      xr = input_r[xbase * 2]; xi = input_r[xbase * 2 + 1];
      cr = C_r[cbase * 2];     ci = C_r[cbase * 2 + 1];
      float reb = cr * xr - ci * xi, imb = cr * xi + ci * xr;   // Xc[a,0]
      Apack[aidx(c, a, 127)]       = f2bf(reb);    // Re XcC[128]
      Apack[aidx(c, a, 255)]       = f2bf(imb);    // -Im XcS[128] = +Im Xc0
      Apack[aidx(c, 256 + a, 127)] = f2bf(imb);    // Im XcC[128]
      Apack[aidx(c, 256 + a, 255)] = f2bf(-reb);   // Re XcS[128] = -Re Xc0
    } else {
      const int bp = 128 + j, bm = 128 - j;
      float xpr = input_r[(xbase + bp) * 2], xpi = input_r[(xbase + bp) * 2 + 1];
      float cpr = C_r[(cbase + bp) * 2],     cpi = C_r[(cbase + bp) * 2 + 1];
      float pr = cpr * xpr - cpi * xpi, pi = cpr * xpi + cpi * xpr;
      float xmr = input_r[(xbase + bm) * 2], xmi = input_r[(xbase + bm) * 2 + 1];
      float cmr = C_r[(cbase + bm) * 2],     cmi = C_r[(cbase + bm) * 2 + 1];
      float mrv = cmr * xmr - cmi * xmi, miv = cmr * xmi + cmi * xmr;
      Apack[aidx(c, a, j - 1)]         = f2bf(pr + mrv);   //  Re XcC[j]
      Apack[aidx(c, a, 127 + j)]       = f2bf(miv - pi);   // -Im XcS[j]
      Apack[aidx(c, 256 + a, j - 1)]   = f2bf(pi + miv);   //  Im XcC[j]
      Apack[aidx(c, 256 + a, 127 + j)] = f2bf(pr - mrv);   //  Re XcS[j]
    }
  } else {
    const int k = bx - 1024;             // 0..17407
    const int kt = k >> 6, kl = k & 63;
    const float s = angle[k * 2 + 0];
    const float t = angle[k * 2 + 1];
    float sn, cs;
    __sincosf(s * (float)(tid - 128), &sn, &cs);   // E1[k, a=tid]
    E1tab[(size_t)k * 256 + tid] =
        (unsigned int)f2bf(cs) | ((unsigned int)f2bf(sn) << 16);
    if (tid >= 1 && tid <= 128) {
      __sincosf(t * (float)tid, &sn, &cs);
      BT[bidx(kt, kl, tid - 1)]   = f2bf(cs);   // cos cols 0..127
      BT[bidx(kt, kl, 127 + tid)] = f2bf(sn);   // sin cols 128..255
    }
  }
}

__global__ __launch_bounds__(512, 4) void gemm_fused(
    const unsigned short* __restrict__ Apack,
    const unsigned short* __restrict__ BT,
    const float* __restrict__ biastab,
    const unsigned int* __restrict__ E1tab,
    const float* __restrict__ wvec,
    float* __restrict__ out)
{
  __shared__ unsigned short As[2][16384];  // 2 x 32 KB A double-buffer
  __shared__ unsigned short Bs[2][2048];   // 2 x 4 KB B double-buffer
  __shared__ float scol[8][2][64];         // 4 KB  => 76 KB -> 2 blocks/CU

  // XCD-aware decode: bx%8 == ktile%8. 2176 = 34*64 -> bijective.
  const int bx = blockIdx.x;
  const int c = (bx >> 3) & 7;
  const int ktile = (bx >> 6) * 8 + (bx & 7);   // 0..271
  const int kt0 = ktile * 64;
  const int tid = threadIdx.x;
  const int w = tid >> 6;       // 0..7: owns logical rows w*64..+63
  const int l = tid & 63;
  const int lhi = l >> 4;       // 0..3
  const int llo = l & 15;
  const int lr = l >> 3;                      // staging: phys row within chunk
  const int lsw = ((l & 7) ^ lr) * 8;         // staging: swizzled source slot

  const unsigned short* Aimg = Apack + (size_t)c * (8 * 16384);
  const unsigned short* Bimg = BT + (size_t)ktile * (8 * 2048);
  const float* biasp = biastab + c * 512 + w * 64 + lhi * 4;

  // fragment read: phys row p, content slot s=((llo&1)<<2)|lhi at position
  // u = s ^ (p&7); p&7 = (llo>>1)&7 (row bases are multiples of 8)
  const int u8 = ((((llo & 1) << 2) | lhi) ^ ((llo >> 1) & 7)) * 8;
  const int plbase = llo >> 1;

  f32x4 acc[4][4];
  // acc init = bias (folded cos-col-0 rank-1 term; k-independent)
#pragma unroll
  for (int fi = 0; fi < 4; ++fi) {
    f32x4 b4 = *(const f32x4*)(biasp + fi * 16);
#pragma unroll
    for (int fj = 0; fj < 4; ++fj) acc[fi][fj] = b4;
  }

  // Prologue: stage tile 0. A chunks are wave-private (wave w: 4 chunks =
  // phys rows w*32..+31); B chunk w staged by waves 0..3.
#pragma unroll
  for (int i = 0; i < 4; ++i) {
    int row0 = (w * 4 + i) * 8;
    async_copy16(&As[0][row0 * 64], Aimg + (size_t)(row0 + lr) * 64 + lsw);
  }
  if (w < 4)
    async_copy16(&Bs[0][w * 8 * 64], Bimg + (size_t)(w * 8 + lr) * 64 + lsw);
  __syncthreads();

#pragma unroll 2
  for (int tt = 0; tt < NT; ++tt) {
    const int cu = tt & 1;
    // Stage tile tt+1 FIRST (fire-and-forget; drained by the end-of-tile
    // __syncthreads, a full compute phase later).
    if (tt < NT - 1) {
      const unsigned short* Asrc = Aimg + (size_t)(tt + 1) * 16384;
      const unsigned short* Bsrc = Bimg + (size_t)(tt + 1) * 2048;
#pragma unroll
      for (int i = 0; i < 4; ++i) {
        int row0 = (w * 4 + i) * 8;
        async_copy16(&As[cu ^ 1][row0 * 64],
                     Asrc + (size_t)(row0 + lr) * 64 + lsw);
      }
      if (w < 4)
        async_copy16(&Bs[cu ^ 1][w * 8 * 64],
                     Bsrc + (size_t)(w * 8 + lr) * 64 + lsw);
    }
    __builtin_amdgcn_sched_barrier(0);   // staging issue stays above compute

    bf16x8 bfr[4];
#pragma unroll
    for (int fj = 0; fj < 4; ++fj)
      bfr[fj] = *(const bf16x8*)&Bs[cu][(fj * 8 + plbase) * 64 + u8];
    bf16x8 af[4];
#pragma unroll
    for (int fi = 0; fi < 4; ++fi)
      af[fi] = *(const bf16x8*)&As[cu][(w * 32 + fi * 8 + plbase) * 64 + u8];
#pragma unroll
    for (int fi = 0; fi < 4; ++fi)
#pragma unroll
      for (int fj = 0; fj < 4; ++fj)
        acc[fi][fj] = __builtin_amdgcn_mfma_f32_16x16x32_bf16(
            af[fi], bfr[fj], acc[fi][fj], 0, 0, 0);
    __syncthreads();
  }

  // Epilogue: wave w holds T rows m = w*64 + fi*16 + lhi*4 + r.
  // w<4: Tr (a = m); w>=4: Ti (a = m-256). Per col: S_r = sum E1r*v,
  // S_i = sum E1i*v over this wave's 64 rows.
  const int aoff = (w & 3) * 64;
#pragma unroll
  for (int fj = 0; fj < 4; ++fj) {
    const int col = fj * 16 + llo;
    const int k = kt0 + col;
    float sumr = 0.f, sumi = 0.f;
    const unsigned int* e1base = E1tab + (size_t)k * 256 + aoff + lhi * 4;
#pragma unroll
    for (int fi = 0; fi < 4; ++fi) {
      uint4 e4 = *(const uint4*)(e1base + fi * 16);
      unsigned int ev[4] = {e4.x, e4.y, e4.z, e4.w};
#pragma unroll
      for (int r = 0; r < 4; ++r) {
        float v = acc[fi][fj][r];
        sumr += bf2f(ev[r] & 0xFFFFu) * v;
        sumi += bf2f(ev[r] >> 16) * v;
      }
    }
    sumr += __shfl_xor(sumr, 16, 64);
    sumr += __shfl_xor(sumr, 32, 64);
    sumi += __shfl_xor(sumi, 16, 64);
    sumi += __shfl_xor(sumi, 32, 64);
    if (lhi == 0) {
      scol[w][0][col] = sumr;
      scol[w][1][col] = sumi;
    }
  }
  __syncthreads();
  if (tid < 128) {
    const int col = tid >> 1;
    const int comp = tid & 1;
    const int k = kt0 + col;
    // Re = sum_{w<4} S_r(w) - sum_{w>=4} S_i(w)
    // Im = sum_{w<4} S_i(w) + sum_{w>=4} S_r(w)
    float re = scol[0][0][col] + scol[1][0][col] + scol[2][0][col] + scol[3][0][col]
             - scol[4][1][col] - scol[5][1][col] - scol[6][1][col] - scol[7][1][col];
    float im = scol[0][1][col] + scol[1][1][col] + scol[2][1][col] + scol[3][1][col]
             + scol[4][0][col] + scol[5][0][col] + scol[6][0][col] + scol[7][0][col];
    float val = comp ? im : re;
    out[((size_t)c * NKTOT + k) * 2 + comp] = val * wvec[k & 511];
  }
}

extern "C" void kernel_launch(void* const* d_in, const int* in_sizes, int n_in,
                              void* d_out, int out_size, void* d_ws, size_t ws_size,
                              hipStream_t stream) {
  const float* input_r = (const float*)d_in[0];  // (256,256,2)
  const float* C_r     = (const float*)d_in[1];  // (8,256,256,2)
  const float* wvec    = (const float*)d_in[2];  // (512,)
  const float* angle   = (const float*)d_in[3];  // (17408,2)
  float* out = (float*)d_out;                    // (8,17408,2)

  // workspace: Apack 2MB | BT 272*8*4KB = 8.9MB | biastab 16KB |
  //            E1tab 17.8MB  => ~28.7MB
  unsigned short* Apack = (unsigned short*)d_ws;
  unsigned short* BT    = (unsigned short*)((char*)d_ws + (size_t)2097152);
  float*       biastab  = (float*)((char*)d_ws + (size_t)11010048);
  unsigned int* E1tab   = (unsigned int*)((char*)d_ws + (size_t)11026432);

  pack_all<<<1024 + NKTOT, 256, 0, stream>>>(input_r, C_r, angle,
                                             Apack, BT, biastab, E1tab);
  gemm_fused<<<8 * NBLK, 512, 0, stream>>>(Apack, BT, biastab, E1tab, wvec, out);
}

// Round 10
// 114.837 us; speedup vs baseline: 1.3412x; 1.2094x over previous
//
#include <hip/hip_runtime.h>
#include <hip/hip_bf16.h>
#include <stdint.h>

// y[c,k] = sum_{a,b} E1[k,a] * Xc[c,a,b] * E2[k,b],  Xc = C*x, E = exp(i*angle*g)
//
// R10 = R9's gemm skeleton (best measured: dbuf gload_lds A-staging, per-tile
// syncthreads, acc[4][4], 512thr/(512,4), XCD decode, bias fold, K=256) with
// the B and E1 TABLES DELETED — computed on the fly on the idle VALU/trans
// pipe (R9 counters: VALUBusy 25%, MfmaUtil 19%, nothing saturated):
//  - B tile: per thread per round 4 cos/sin + one 8B ds_write directly into
//    the XOR-swizzled LDS slot (we control the address; no gload_lds
//    constraint). t=angle[k,1] loaded once per thread. Kills BT (8.9MB HBM
//    + 70MB L2 + staging VMEM + its share of the drain).
//  - E1 in epilogue, factored: S = e^{i s a0} * sum_fi e^{i16s fi} *
//    (sum_r e^{i s r} v[fi][r]) -> 2 sincos + ~70 fma per (lane,col).
//    Kills E1tab (17.8MB HBM + 139MB L2).
//  - pack shrinks to the A-fold only (1024 blocks); workspace 30MB -> 2.1MB.
//
// A content per (c,a): A_re row a     = [Re XcC[j] | -Im XcS[j]], j=1..128
//                      A_im row 256+a = [Im XcC[j] |  Re XcS[j]]
//   XcC[j]=Xc[128+j]+Xc[128-j], XcS[j]=Xc[128+j]-Xc[128-j] (j=1..127)
//   XcC[128]=Xc[b=0], XcS[128]=-Xc[b=0];  bias row = Xc[a,b=128] (g=0 term)

#define NKTOT 17408
#define NBLK 272    // ktiles of 64 k-values
#define NT 8        // K-tiles of 32 (K = 256 exactly)

typedef short bf16x8 __attribute__((ext_vector_type(8)));
typedef float f32x4 __attribute__((ext_vector_type(4)));

__device__ __forceinline__ unsigned short f2bf(float f) {
  unsigned int u = __builtin_bit_cast(unsigned int, f);
  u += 0x7FFFu + ((u >> 16) & 1u);
  return (unsigned short)(u >> 16);
}

__device__ __forceinline__ void async_copy16(void* lds, const void* g) {
  __builtin_amdgcn_global_load_lds(
      (const __attribute__((address_space(1))) unsigned int*)g,
      (__attribute__((address_space(3))) unsigned int*)lds, 16, 0, 0);
}

// A image: [c][tt<8][p<256][s<8][e<8] ushorts.
//   logical row m (0..511): p=m>>1 ; col jj (0..255): tt=jj>>5,
//   s=((m&1)<<2)|((jj>>3)&3), e=jj&7
__device__ __forceinline__ size_t aidx(int c, int m, int jj) {
  int tt = jj >> 5;
  int s = ((m & 1) << 2) | ((jj >> 3) & 3);
  return (((size_t)(c * 8 + tt) * 256 + (m >> 1)) * 8 + s) * 8 + (jj & 7);
}

// A fold + bias only (B/E1 now computed inside gemm).
__global__ __launch_bounds__(256) void pack_a(
    const float* __restrict__ input_r, const float* __restrict__ C_r,
    unsigned short* __restrict__ Apack, float* __restrict__ biastab)
{
  const int bx = blockIdx.x;           // 0..1023
  const int tid = threadIdx.x;
  const int p = bx * 2 + (tid >> 7);   // (c,a) pair index 0..2047
  const int a = p & 255;
  const int c = p >> 8;
  const int j = tid & 127;
  const size_t xbase = (size_t)a * 256;
  const size_t cbase = ((size_t)(c * 256 + a)) * 256;
  if (j == 0) {
    // bias (b=128, g=0) and the unpaired b=0 (g=-128) fold
    float xr = input_r[(xbase + 128) * 2], xi = input_r[(xbase + 128) * 2 + 1];
    float cr = C_r[(cbase + 128) * 2],     ci = C_r[(cbase + 128) * 2 + 1];
    biastab[c * 512 + a]       = cr * xr - ci * xi;   // Re Xc[a,128]
    biastab[c * 512 + 256 + a] = cr * xi + ci * xr;   // Im Xc[a,128]
    xr = input_r[xbase * 2]; xi = input_r[xbase * 2 + 1];
    cr = C_r[cbase * 2];     ci = C_r[cbase * 2 + 1];
    float reb = cr * xr - ci * xi, imb = cr * xi + ci * xr;   // Xc[a,0]
    Apack[aidx(c, a, 127)]       = f2bf(reb);    // Re XcC[128]
    Apack[aidx(c, a, 255)]       = f2bf(imb);    // -Im XcS[128] = +Im Xc0
    Apack[aidx(c, 256 + a, 127)] = f2bf(imb);    // Im XcC[128]
    Apack[aidx(c, 256 + a, 255)] = f2bf(-reb);   // Re XcS[128] = -Re Xc0
  } else {
    const int bp = 128 + j, bm = 128 - j;
    float xpr = input_r[(xbase + bp) * 2], xpi = input_r[(xbase + bp) * 2 + 1];
    float cpr = C_r[(cbase + bp) * 2],     cpi = C_r[(cbase + bp) * 2 + 1];
    float pr = cpr * xpr - cpi * xpi, pi = cpr * xpi + cpi * xpr;
    float xmr = input_r[(xbase + bm) * 2], xmi = input_r[(xbase + bm) * 2 + 1];
    float cmr = C_r[(cbase + bm) * 2],     cmi = C_r[(cbase + bm) * 2 + 1];
    float mrv = cmr * xmr - cmi * xmi, miv = cmr * xmi + cmi * xmr;
    Apack[aidx(c, a, j - 1)]         = f2bf(pr + mrv);   //  Re XcC[j]
    Apack[aidx(c, a, 127 + j)]       = f2bf(miv - pi);   // -Im XcS[j]
    Apack[aidx(c, 256 + a, j - 1)]   = f2bf(pi + miv);   //  Im XcC[j]
    Apack[aidx(c, 256 + a, 127 + j)] = f2bf(pr - mrv);   //  Re XcS[j]
  }
}

// Compute one round's B tile (64 k x 32 cols) straight into the swizzled LDS
// buffer. Thread (w,l): k-row kl=l, cols jl = w*4..w*4+3 of tile `tile`.
// Content col jj = tile*32+jl: jj<128 -> cos(t*(jj+1)); else sin(t*(jj-127));
// both reduce to trig(t * ((tile&3)*32 + jl + 1)).
// Layout (matches reader): p=kl>>1, content slot s=((kl&1)<<2)|(jl>>3),
// stored at u = s ^ (p&7), e = jl&7 (= (w&1)*4 + q, one aligned 8B span).
__device__ __forceinline__ void b_compute(unsigned short* buf, float t,
                                          int tile, int w, int l) {
  const int p = l >> 1;
  const int u = ((((l & 1) << 2) | (w >> 1)) ^ (p & 7));
  const float jb = (float)((tile & 3) * 32 + w * 4 + 1);
  float v0, v1, v2, v3;
  if (tile < 4) {
    v0 = __cosf(t * jb);
    v1 = __cosf(t * (jb + 1.f));
    v2 = __cosf(t * (jb + 2.f));
    v3 = __cosf(t * (jb + 3.f));
  } else {
    v0 = __sinf(t * jb);
    v1 = __sinf(t * (jb + 1.f));
    v2 = __sinf(t * (jb + 2.f));
    v3 = __sinf(t * (jb + 3.f));
  }
  uint2 pk;
  pk.x = (unsigned int)f2bf(v0) | ((unsigned int)f2bf(v1) << 16);
  pk.y = (unsigned int)f2bf(v2) | ((unsigned int)f2bf(v3) << 16);
  *(uint2*)(buf + p * 64 + u * 8 + (w & 1) * 4) = pk;
}

__global__ __launch_bounds__(512, 4) void gemm_fused(
    const unsigned short* __restrict__ Apack,
    const float* __restrict__ biastab,
    const float* __restrict__ angle,
    const float* __restrict__ wvec,
    float* __restrict__ out)
{
  __shared__ unsigned short As[2][16384];  // 2 x 32 KB A double-buffer
  __shared__ unsigned short Bs[2][2048];   // 2 x 4 KB B double-buffer
  __shared__ float scol[8][2][64];         // 4 KB  => 76 KB -> 2 blocks/CU

  // XCD-aware decode: bx%8 == ktile%8. 2176 = 34*64 -> bijective.
  const int bx = blockIdx.x;
  const int c = (bx >> 3) & 7;
  const int ktile = (bx >> 6) * 8 + (bx & 7);   // 0..271
  const int kt0 = ktile * 64;
  const int tid = threadIdx.x;
  const int w = tid >> 6;       // 0..7: owns logical rows w*64..+63
  const int l = tid & 63;
  const int lhi = l >> 4;       // 0..3
  const int llo = l & 15;
  const int lr = l >> 3;                      // staging: phys row within chunk
  const int lsw = ((l & 7) ^ lr) * 8;         // staging: swizzled source slot

  const unsigned short* Aimg = Apack + (size_t)c * (8 * 16384);
  const float* biasp = biastab + c * 512 + w * 64 + lhi * 4;

  // fragment read: phys row p, content slot s=((llo&1)<<2)|lhi at u=s^(p&7)
  const int u8 = ((((llo & 1) << 2) | lhi) ^ ((llo >> 1) & 7)) * 8;
  const int plbase = llo >> 1;

  // per-thread B angle (k = kt0 + l), loaded once
  const float t_reg = angle[(size_t)(kt0 + l) * 2 + 1];

  f32x4 acc[4][4];
  // acc init = bias (folded cos-col-0 rank-1 term; k-independent)
#pragma unroll
  for (int fi = 0; fi < 4; ++fi) {
    f32x4 b4 = *(const f32x4*)(biasp + fi * 16);
#pragma unroll
    for (int fj = 0; fj < 4; ++fj) acc[fi][fj] = b4;
  }

  // Prologue: stage A tile 0 (wave-private chunks); compute B tile 0.
#pragma unroll
  for (int i = 0; i < 4; ++i) {
    int row0 = (w * 4 + i) * 8;
    async_copy16(&As[0][row0 * 64], Aimg + (size_t)(row0 + lr) * 64 + lsw);
  }
  b_compute(&Bs[0][0], t_reg, 0, w, l);
  __syncthreads();

#pragma unroll 2
  for (int tt = 0; tt < NT; ++tt) {
    const int cu = tt & 1;
    // Stage A tile tt+1 FIRST (fire-and-forget; drained by the end-of-tile
    // __syncthreads, a full compute phase later).
    if (tt < NT - 1) {
      const unsigned short* Asrc = Aimg + (size_t)(tt + 1) * 16384;
#pragma unroll
      for (int i = 0; i < 4; ++i) {
        int row0 = (w * 4 + i) * 8;
        async_copy16(&As[cu ^ 1][row0 * 64],
                     Asrc + (size_t)(row0 + lr) * 64 + lsw);
      }
    }
    __builtin_amdgcn_sched_barrier(0);   // staging issue stays above compute

    bf16x8 bfr[4];
#pragma unroll
    for (int fj = 0; fj < 4; ++fj)
      bfr[fj] = *(const bf16x8*)&Bs[cu][(fj * 8 + plbase) * 64 + u8];
    bf16x8 af[4];
#pragma unroll
    for (int fi = 0; fi < 4; ++fi)
      af[fi] = *(const bf16x8*)&As[cu][(w * 32 + fi * 8 + plbase) * 64 + u8];
#pragma unroll
    for (int fi = 0; fi < 4; ++fi)
#pragma unroll
      for (int fj = 0; fj < 4; ++fj)
        acc[fi][fj] = __builtin_amdgcn_mfma_f32_16x16x32_bf16(
            af[fi], bfr[fj], acc[fi][fj], 0, 0, 0);

    // Compute next B tile into the other buffer (VALU/trans + 1 ds_write;
    // overlaps MFMA latency; consumed only after the barrier).
    if (tt < NT - 1) b_compute(&Bs[cu ^ 1][0], t_reg, tt + 1, w, l);
    __syncthreads();
  }

  // Epilogue: wave w holds T rows m = w*64 + fi*16 + lhi*4 + r
  // (w<4: Tr, a=m; w>=4: Ti, a=m-256). E1 factored on the fly:
  //   S = e^{i s a0} * sum_fi e^{i 16 s fi} * (sum_r e^{i s r} v[fi][r]),
  //   a0 = (w&3)*64 + lhi*4 - 128, s = angle[k,0].
  const int aoff = (w & 3) * 64;
  const float a0f = (float)(aoff + lhi * 4 - 128);
#pragma unroll
  for (int fj = 0; fj < 4; ++fj) {
    const int col = fj * 16 + llo;
    const int k = kt0 + col;
    const float s = angle[(size_t)k * 2];
    float s1, c1;
    __sincosf(s, &s1, &c1);
    // e^{i2s}, e^{i3s} from e^{is}
    float c2 = c1 * c1 - s1 * s1, s2 = 2.f * c1 * s1;
    float c3 = c2 * c1 - s2 * s1, s3 = c2 * s1 + s2 * c1;
    // e^{i16s} via squarings; then e^{i32s}, e^{i48s}
    float c4 = c2 * c2 - s2 * s2,  s4 = 2.f * c2 * s2;
    float c8 = c4 * c4 - s4 * s4,  s8 = 2.f * c4 * s4;
    float cY = c8 * c8 - s8 * s8,  sY = 2.f * c8 * s8;     // 16s
    float cY2 = cY * cY - sY * sY, sY2 = 2.f * cY * sY;    // 32s
    float cY3 = cY2 * cY - sY2 * sY, sY3 = cY2 * sY + sY2 * cY;  // 48s
    const float Yr[4] = {1.f, cY, cY2, cY3};
    const float Yi[4] = {0.f, sY, sY2, sY3};
    float Or = 0.f, Oi = 0.f;
#pragma unroll
    for (int fi = 0; fi < 4; ++fi) {
      float v0 = acc[fi][fj][0], v1 = acc[fi][fj][1];
      float v2 = acc[fi][fj][2], v3 = acc[fi][fj][3];
      float Ir = v0 + c1 * v1 + c2 * v2 + c3 * v3;
      float Ii = s1 * v1 + s2 * v2 + s3 * v3;
      Or += Yr[fi] * Ir - Yi[fi] * Ii;
      Oi += Yi[fi] * Ir + Yr[fi] * Ii;
    }
    float sb, cb;
    __sincosf(s * a0f, &sb, &cb);
    float sumr = cb * Or - sb * Oi;
    float sumi = sb * Or + cb * Oi;
    sumr += __shfl_xor(sumr, 16, 64);
    sumr += __shfl_xor(sumr, 32, 64);
    sumi += __shfl_xor(sumi, 16, 64);
    sumi += __shfl_xor(sumi, 32, 64);
    if (lhi == 0) {
      scol[w][0][col] = sumr;
      scol[w][1][col] = sumi;
    }
  }
  __syncthreads();
  if (tid < 128) {
    const int col = tid >> 1;
    const int comp = tid & 1;
    const int k = kt0 + col;
    // Re = sum_{w<4} S_r(w) - sum_{w>=4} S_i(w)
    // Im = sum_{w<4} S_i(w) + sum_{w>=4} S_r(w)
    float re = scol[0][0][col] + scol[1][0][col] + scol[2][0][col] + scol[3][0][col]
             - scol[4][1][col] - scol[5][1][col] - scol[6][1][col] - scol[7][1][col];
    float im = scol[0][1][col] + scol[1][1][col] + scol[2][1][col] + scol[3][1][col]
             + scol[4][0][col] + scol[5][0][col] + scol[6][0][col] + scol[7][0][col];
    float val = comp ? im : re;
    out[((size_t)c * NKTOT + k) * 2 + comp] = val * wvec[k & 511];
  }
}

extern "C" void kernel_launch(void* const* d_in, const int* in_sizes, int n_in,
                              void* d_out, int out_size, void* d_ws, size_t ws_size,
                              hipStream_t stream) {
  const float* input_r = (const float*)d_in[0];  // (256,256,2)
  const float* C_r     = (const float*)d_in[1];  // (8,256,256,2)
  const float* wvec    = (const float*)d_in[2];  // (512,)
  const float* angle   = (const float*)d_in[3];  // (17408,2)
  float* out = (float*)d_out;                    // (8,17408,2)

  // workspace: Apack 2MB | biastab 16KB  => ~2.1MB
  unsigned short* Apack = (unsigned short*)d_ws;
  float* biastab = (float*)((char*)d_ws + (size_t)2097152);

  pack_a<<<1024, 256, 0, stream>>>(input_r, C_r, Apack, biastab);
  gemm_fused<<<8 * NBLK, 512, 0, stream>>>(Apack, biastab, angle, wvec, out);
}